// Round 13
// baseline (136.748 us; speedup 1.0000x reference)
//
#include <hip/hip_runtime.h>
#include <stdint.h>
#include <stddef.h>

// y[n,o] = sum_i x[n,i]*W[n,i,o] + b[n,o];  W = (x@Ww+bw) reshaped; b = x@Wb+bb.
// => Y = A@B (+bb): A[n, j*128+i] = x[n,i]*x[n,j]; B = Ww viewed [16384,128] row-major,
//    K-tail of 128: A[n,16384+i]=x[n,i], B[16384+i,o]=Wb[i,o]+bw[i*128+o].
// ROUND 20: r19 A/B showed setprio+hoist cost 3us -> dropped. r16 (48.2us gemm) is the
// register-prefetch structure's floor (MfmaUtil pinned ~28%). Last mechanism-backed
// lever: B via LDS staging (m97/T3 family, measured 37%+ MfmaUtil):
//  - removes the wm-duplication (every B fragment currently fetched by BOTH wm waves);
//  - global_load_lds(16B) linear staging, g_B PRE-SWIZZLED in prep (rule 21: linear
//    dest + pre-swizzled source + swizzled ds_read); frag reads 2-way-max conflicts;
//  - counted-vmcnt pipeline (T4): stage(h+2) per half-step, s_waitcnt vmcnt(2) at step
//    top (0 only at last step), raw s_barrier + manual lgkmcnt(0) (no __syncthreads
//    drain). In-loop vmcnt ops = staging builtins only -> counts exact.
//  - LDS exactly 64KB: xs[128*128] XOR-swizzled + bs[2][2][8KB]; 2 blocks/CU kept.
// MFMA/numerics identical to r16. Epilogue/finish/grid unchanged.

#define NROWS   8192
#define NKT     516            // (16384+128)/32 K-tiles
#define TILE_E  4096           // 128 cols x 32 kk per K-tile image (u16)
#define LS_STRIDE 136
#define BM      128
#define NSLICE  8

typedef unsigned short u16;
typedef short short8 __attribute__((ext_vector_type(8)));
typedef unsigned short ushort8 __attribute__((ext_vector_type(8)));
typedef float floatx4 __attribute__((ext_vector_type(4)));

typedef __attribute__((address_space(1))) const unsigned int as1_u32;
typedef __attribute__((address_space(3))) unsigned int as3_u32;

// Module-scope scratch (BSS; independent of d_ws — rounds 1-3 showed ws hazards).
__device__ __align__(16) u16   g_B[(size_t)NKT * TILE_E];                    // 4.2 MB bf16 B image (swizzled tiles)
__device__ __align__(16) float g_P[(size_t)NSLICE * NROWS * 128];            // 33.5 MB fp32 partials

__device__ __forceinline__ u16 f2bf_rne(float f) {
    unsigned int u = __float_as_uint(f);
    u += 0x7fffu + ((u >> 16) & 1u);
    return (u16)(u >> 16);
}

// ---------------- prep: g_B[kt] = swizzled image of B[kt*32+kk][o] in [o][kk] order.
// Chunk (8 u16) at index i stored at i ^ ((o&7)<<3) — involution; gemm stages the tile
// LINEARLY into LDS and reads fragments with the same XOR -> original data.
__global__ __launch_bounds__(256) void prep_kernel(
    const float* __restrict__ Ww, const float* __restrict__ Wb,
    const float* __restrict__ bw)
{
    __shared__ __align__(16) u16 ls[32 * LS_STRIDE];
    const int kt = blockIdx.x;
    const int t  = threadIdx.x;

    // load 16 contiguous floats -> bf16, store to ls[kk][o] (padded stride)
    float v[16];
    if (kt < 512) {
        const float* src = Ww + (size_t)(kt >> 2)*16384 + (size_t)(kt & 3)*32*128 + t*16;
#pragma unroll
        for (int c = 0; c < 4; ++c) {
            const floatx4 f4 = *(const floatx4*)(src + c*4);
#pragma unroll
            for (int e = 0; e < 4; ++e) v[c*4 + e] = f4[e];
        }
    } else {
        const size_t base = (size_t)(kt - 512)*32*128 + t*16;
        const float* s1 = Wb + base;
        const float* s2 = bw + base;
#pragma unroll
        for (int c = 0; c < 4; ++c) {
            const floatx4 a = *(const floatx4*)(s1 + c*4);
            const floatx4 b = *(const floatx4*)(s2 + c*4);
#pragma unroll
            for (int e = 0; e < 4; ++e) v[c*4 + e] = a[e] + b[e];
        }
    }
    {
        const int kk = t >> 3;            // f = t*16 -> kk = f>>7
        const int o0 = (t & 7) * 16;      // f & 127
        ushort8 w0, w1;
#pragma unroll
        for (int e = 0; e < 8; ++e) { w0[e] = f2bf_rne(v[e]); w1[e] = f2bf_rne(v[8+e]); }
        *(ushort8*)&ls[kk*LS_STRIDE + o0]     = w0;
        *(ushort8*)&ls[kk*LS_STRIDE + o0 + 8] = w1;
    }
    __syncthreads();
    // write out [o][kk] with chunk-XOR swizzle: thread t covers o = t>>1, kk0 = (t&1)*16
    {
        const int o   = t >> 1;
        const int kk0 = (t & 1) * 16;
        ushort8 w0, w1;
#pragma unroll
        for (int e = 0; e < 8; ++e) {
            w0[e] = ls[(kk0 + e)*LS_STRIDE + o];
            w1[e] = ls[(kk0 + 8 + e)*LS_STRIDE + o];
        }
        u16* base = g_B + (size_t)kt*TILE_E;
        const int swz = (o & 7) << 3;
        *(ushort8*)&base[(o*32 + kk0    ) ^ swz] = w0;
        *(ushort8*)&base[(o*32 + kk0 + 8) ^ swz] = w1;
    }
}

// ---------------- gemm: 8-wave block, 128x128 tile, LDS-staged B, counted vmcnt ------
// grid 512 = slice(8) x rowblock(64). Half-step = 2 kt (16KB staged block-wide).
// Pipeline: stage(h), stage(h+1) in flight; step h: vmcnt(2) [stage(h) done], barrier,
// ds_read frags, lgkmcnt(0), barrier [readers done], issue stage(h+2) into same buf,
// 16 MFMA; odd halves run the xj*aj->acc phase tail. Last step: vmcnt(0).
__global__ __launch_bounds__(512, 2) void gemm_kernel(const float* __restrict__ x)
{
    __shared__ __align__(16) u16 xs[128 * 128];      // 32 KB, row-XOR-swizzled
    __shared__ __align__(16) u16 bs[2 * 2 * 4096];   // 32 KB: 2 bufs x 2 kt x 8KB

    const int b     = blockIdx.x;
    const int slice = b >> 6;         // 0..7
    const int rb    = b & 63;         // 0..63
    const int row0  = rb * BM;
    const int tid   = threadIdx.x;
    const int lane  = tid & 63;
    const int wave  = tid >> 6;       // 0..7 (uniform per wave)
    const int wm    = wave >> 2;      // row group: rows [wm*64, +64)
    const int wc    = wave & 3;       // col subgroup: cols [wc*32, +32)
    const int l15   = lane & 15;
    const int q     = lane >> 4;

    // stage x[row0..+128)[0..128) fp32 -> bf16 xs, XOR-swizzled (idx ^= (row&7)<<3)
#pragma unroll
    for (int it = 0; it < 4; ++it) {
        const int c  = it*512 + tid;
        const int r  = c >> 4;
        const int c8 = (c & 15) * 8;
        const float* sp = x + ((size_t)(row0 + r) << 7) + c8;
        const floatx4 f0 = *(const floatx4*)(sp);
        const floatx4 f1 = *(const floatx4*)(sp + 4);
        ushort8 w;
#pragma unroll
        for (int e = 0; e < 4; ++e) { w[e] = f2bf_rne(f0[e]); w[4+e] = f2bf_rne(f1[e]); }
        *(ushort8*)&xs[(r*128 + c8) ^ ((r & 7) << 3)] = w;
    }
    __syncthreads();   // full drain OK here (before any counted staging)

    // A-fragments cached (phase-invariant): af[ks][mt]
    short8 af[4][4];
#pragma unroll
    for (int ks = 0; ks < 4; ++ks)
#pragma unroll
        for (int mt = 0; mt < 4; ++mt) {
            const int row = wm*64 + mt*16 + l15;
            af[ks][mt] = *(const short8*)&xs[(row*128 + ks*32 + q*8) ^ ((l15 & 7) << 3)];
        }

    const floatx4 fzero = {0.f, 0.f, 0.f, 0.f};
    floatx4 acc[4][2];
#pragma unroll
    for (int i = 0; i < 4; ++i) { acc[i][0] = fzero; acc[i][1] = fzero; }
    floatx4 aj[4][2];

    // phase partition: 129 phases over 8 slices (17,16,16,16,16,16,16,16)
    const int p0 = slice*16 + (slice ? 1 : 0);
    const int np = slice ? 16 : 17;

    const int colbase = wc*32;
    const int swz8 = (l15 & 7) << 3;
    const int idx0 = ((colbase + l15     ) * 32 + q*8) ^ swz8;   // nt=0 frag (u16 idx)
    const int idx1 = ((colbase + l15 + 16) * 32 + q*8) ^ swz8;   // nt=1 frag

    // stage one half (2 kt = 16KB) linearly: 2 x global_load_lds(16B) per thread
#define STAGE(BUF, KT)                                                                 \
    {                                                                                  \
        const u16* g0 = g_B + (size_t)(KT)*TILE_E + (size_t)(wave*64 + lane)*8;        \
        _Pragma("unroll")                                                              \
        for (int i = 0; i < 2; ++i)                                                    \
            __builtin_amdgcn_global_load_lds((as1_u32*)(g0 + i*4096),                  \
                (as3_u32*)&bs[(BUF)*8192 + i*4096 + wave*512], 16, 0, 0);              \
    }

#define STEP(BUF, ISODD, DOISSUE, WN, PIDX, KTI)                                       \
    {                                                                                  \
        asm volatile("s_waitcnt vmcnt(%0)" :: "n"(WN) : "memory");                     \
        __builtin_amdgcn_s_barrier();      /* stage(h) visible to all waves */         \
        short8 f0n0 = *(const short8*)&bs[(BUF)*8192        + idx0];                   \
        short8 f0n1 = *(const short8*)&bs[(BUF)*8192        + idx1];                   \
        short8 f1n0 = *(const short8*)&bs[(BUF)*8192 + 4096 + idx0];                   \
        short8 f1n1 = *(const short8*)&bs[(BUF)*8192 + 4096 + idx1];                   \
        asm volatile("s_waitcnt lgkmcnt(0)" ::: "memory");                             \
        __builtin_amdgcn_s_barrier();      /* all reads done -> buf overwritable */    \
        if (DOISSUE) STAGE(BUF, KTI);                                                  \
        _Pragma("unroll")                                                              \
        for (int mt = 0; mt < 4; ++mt) {                                               \
            aj[mt][0] = __builtin_amdgcn_mfma_f32_16x16x32_bf16(af[(ISODD)*2][mt], f0n0, (ISODD) ? aj[mt][0] : fzero, 0,0,0); \
            aj[mt][1] = __builtin_amdgcn_mfma_f32_16x16x32_bf16(af[(ISODD)*2][mt], f0n1, (ISODD) ? aj[mt][1] : fzero, 0,0,0); \
        }                                                                              \
        _Pragma("unroll")                                                              \
        for (int mt = 0; mt < 4; ++mt) {                                               \
            aj[mt][0] = __builtin_amdgcn_mfma_f32_16x16x32_bf16(af[(ISODD)*2+1][mt], f1n0, aj[mt][0], 0,0,0); \
            aj[mt][1] = __builtin_amdgcn_mfma_f32_16x16x32_bf16(af[(ISODD)*2+1][mt], f1n1, aj[mt][1], 0,0,0); \
        }                                                                              \
        if (ISODD) {                                                                   \
            _Pragma("unroll")                                                          \
            for (int mt = 0; mt < 4; ++mt) {                                           \
                floatx4 xjv;                                                           \
                _Pragma("unroll")                                                      \
                for (int r = 0; r < 4; ++r) {                                          \
                    const int rl = wm*64 + mt*16 + q*4 + r;                            \
                    xjv[r] = ((PIDX) < 128)                                            \
                        ? __uint_as_float(((unsigned int)xs[(rl*128 + (PIDX)) ^ (((q*4 + r) & 7) << 3)]) << 16) \
                        : 1.0f;                                                        \
                }                                                                      \
                acc[mt][0] += xjv * aj[mt][0];                                         \
                acc[mt][1] += xjv * aj[mt][1];                                         \
            }                                                                          \
        }                                                                              \
    }

    // prologue: stage halves 0 (buf0) and 1 (buf1) -> 4 loads in flight
    int kt = p0*4;
    STAGE(0, kt);
    STAGE(1, kt + 2);

    const int nh = np * 2;
    for (int hh = 0; hh < nh - 2; hh += 2) {
        STEP(0, 0, 1, 2, 0,               kt + 4);   // even half of phase hh/2
        STEP(1, 1, 1, 2, p0 + (hh >> 1),  kt + 6);   // odd half + phase tail
        kt += 4;
    }
    // epilogue: last two halves, no new staging; final step drains vmcnt fully
    STEP(0, 0, 0, 2, 0, 0);
    STEP(1, 1, 0, 0, p0 + np - 1, 0);
#undef STEP
#undef STAGE

    // slice-private plain stores (no atomics; region fully overwritten -> no zeroing)
    float* op = g_P + (size_t)slice * ((size_t)NROWS * 128);
#pragma unroll
    for (int mt = 0; mt < 4; ++mt)
#pragma unroll
        for (int nt = 0; nt < 2; ++nt) {
            const int col = colbase + nt*16 + l15;        // C/D: col = lane&15
#pragma unroll
            for (int r = 0; r < 4; ++r) {
                const int row = row0 + wm*64 + mt*16 + q*4 + r;
                op[((size_t)row << 7) + col] = acc[mt][nt][r];
            }
        }
}

// ---------------- finish: reduce 8 slice partials, + bb, write fp32 ----------------
__global__ __launch_bounds__(256) void finish_kernel(
    const float* __restrict__ bb, float* __restrict__ out)
{
    const int flat = (blockIdx.x*256 + threadIdx.x) * 8;
    floatx4 s0 = {0.f, 0.f, 0.f, 0.f};
    floatx4 s1 = {0.f, 0.f, 0.f, 0.f};
#pragma unroll
    for (int s = 0; s < NSLICE; ++s) {
        const float* p = g_P + (size_t)s * ((size_t)NROWS * 128) + flat;
        const floatx4 a = *(const floatx4*)p;
        const floatx4 c = *(const floatx4*)(p + 4);
#pragma unroll
        for (int e = 0; e < 4; ++e) { s0[e] += a[e]; s1[e] += c[e]; }
    }
    const floatx4 b0 = *(const floatx4*)(bb + (flat & 127));
    const floatx4 b1 = *(const floatx4*)(bb + (flat & 127) + 4);
    floatx4 o0, o1;
#pragma unroll
    for (int e = 0; e < 4; ++e) { o0[e] = s0[e] + b0[e]; o1[e] = s1[e] + b1[e]; }
    *(floatx4*)(out + flat)     = o0;
    *(floatx4*)(out + flat + 4) = o1;
}

extern "C" void kernel_launch(void* const* d_in, const int* in_sizes, int n_in,
                              void* d_out, int out_size, void* d_ws, size_t ws_size,
                              hipStream_t stream) {
    (void)in_sizes; (void)n_in; (void)out_size; (void)d_ws; (void)ws_size;
    const float* x  = (const float*)d_in[0];
    const float* Wb = (const float*)d_in[1];
    const float* bb = (const float*)d_in[2];
    const float* Ww = (const float*)d_in[3];
    const float* bw = (const float*)d_in[4];
    float* out = (float*)d_out;

    prep_kernel  <<<dim3(NKT),            dim3(256), 0, stream>>>(Ww, Wb, bw);
    gemm_kernel  <<<dim3(512),            dim3(512), 0, stream>>>(x);
    finish_kernel<<<dim3(NROWS*128/2048), dim3(256), 0, stream>>>(bb, out);
}

// Round 15
// 124.382 us; speedup vs baseline: 1.0994x; 1.0994x over previous
//
#include <hip/hip_runtime.h>
#include <stdint.h>
#include <stddef.h>

// y[n,o] = sum_i x[n,i]*W[n,i,o] + b[n,o];  W = (x@Ww+bw) reshaped; b = x@Wb+bb.
// => Y = A@B (+bb): A[n, j*128+i] = x[n,i]*x[n,j]; B = Ww viewed [16384,128] row-major,
//    K-tail of 128: A[n,16384+i]=x[n,i], B[16384+i,o]=Wb[i,o]+bw[i*128+o].
// Per-j-phase factoring: aj = X_rows·B_j with raw-x fragments, acc += x[row,j]*aj.
// ROUND 22: r21 failed on a NAME COLLISION only (ushort4 is a HIP built-in alias);
// renamed to ushortx4, design unchanged. r21 rationale: r16 (48.2us) pinned at 2
// waves/SIMD by unified regs ~180 (116V+64A); 3 waves needs VGPR<=~106. Free the af
// cache (ks2,3 re-read from LDS per phase — fixed ~12cy DS latency hidden under
// ks0/ks1 MFMAs, no global exposure) instead of r17's mistake (B-prefetch bufs ->
// lost global cover). BM=64 block (4 waves x 32 cols) removes wm B-duplication;
// xt[p][row] transposed x image: xj tail = 4 x ds_read_b64 not 16 x ds_read_u16.
// 4-kt dbuf prefetch / MFMA order / epilogue unchanged from r16.
// Grid 768 = slice(6) x rb(128), 3 blocks/CU, LDS 35KB/block.

#define NROWS   8192
#define NKT     516            // (16384+128)/32 K-tiles
#define TILE_E  4096           // 128 cols x 32 kk per K-tile image (u16)
#define XS_STRIDE 136          // 128 + 8 pad
#define XT_STRIDE 72           // 64 + 8 pad
#define LS_STRIDE 136
#define BM      64
#define NSLICE  6

typedef unsigned short u16;
typedef short short8 __attribute__((ext_vector_type(8)));
typedef unsigned short ushort8 __attribute__((ext_vector_type(8)));
typedef unsigned short ushortx4 __attribute__((ext_vector_type(4)));
typedef float floatx4 __attribute__((ext_vector_type(4)));

// Module-scope scratch (BSS; independent of d_ws — rounds 1-3 showed ws hazards).
__device__ __align__(16) u16   g_B[(size_t)NKT * TILE_E];                    // 4.2 MB bf16 B image
__device__ __align__(16) float g_P[(size_t)NSLICE * NROWS * 128];            // 25 MB fp32 partials

__device__ __forceinline__ u16 f2bf_rne(float f) {
    unsigned int u = __float_as_uint(f);
    u += 0x7fffu + ((u >> 16) & 1u);
    return (u16)(u >> 16);
}

// ---------------- prep: g_B[kt][o][kk] = B[kt*32+kk][o], coalesced via LDS transpose.
__global__ __launch_bounds__(256) void prep_kernel(
    const float* __restrict__ Ww, const float* __restrict__ Wb,
    const float* __restrict__ bw)
{
    __shared__ __align__(16) u16 ls[32 * LS_STRIDE];
    const int kt = blockIdx.x;
    const int t  = threadIdx.x;

    // load 16 contiguous floats -> bf16, store to ls[kk][o] (padded stride)
    float v[16];
    if (kt < 512) {
        const float* src = Ww + (size_t)(kt >> 2)*16384 + (size_t)(kt & 3)*32*128 + t*16;
#pragma unroll
        for (int c = 0; c < 4; ++c) {
            const floatx4 f4 = *(const floatx4*)(src + c*4);
#pragma unroll
            for (int e = 0; e < 4; ++e) v[c*4 + e] = f4[e];
        }
    } else {
        const size_t base = (size_t)(kt - 512)*32*128 + t*16;
        const float* s1 = Wb + base;
        const float* s2 = bw + base;
#pragma unroll
        for (int c = 0; c < 4; ++c) {
            const floatx4 a = *(const floatx4*)(s1 + c*4);
            const floatx4 b = *(const floatx4*)(s2 + c*4);
#pragma unroll
            for (int e = 0; e < 4; ++e) v[c*4 + e] = a[e] + b[e];
        }
    }
    {
        const int kk = t >> 3;            // f = t*16 -> kk = f>>7
        const int o0 = (t & 7) * 16;      // f & 127
        ushort8 w0, w1;
#pragma unroll
        for (int e = 0; e < 8; ++e) { w0[e] = f2bf_rne(v[e]); w1[e] = f2bf_rne(v[8+e]); }
        *(ushort8*)&ls[kk*LS_STRIDE + o0]     = w0;
        *(ushort8*)&ls[kk*LS_STRIDE + o0 + 8] = w1;
    }
    __syncthreads();
    // write out [o][kk]: thread t covers d = t*16..+15 -> o = t>>1, kk = (t&1)*16..+15
    {
        const int o   = t >> 1;
        const int kk0 = (t & 1) * 16;
        ushort8 w0, w1;
#pragma unroll
        for (int e = 0; e < 8; ++e) {
            w0[e] = ls[(kk0 + e)*LS_STRIDE + o];
            w1[e] = ls[(kk0 + 8 + e)*LS_STRIDE + o];
        }
        u16* outp = g_B + (size_t)kt*TILE_E + t*16;
        ((ushort8*)outp)[0] = w0; ((ushort8*)outp)[1] = w1;
    }
}

// ---------------- gemm: 4-wave block, 64x128 tile, dbuf B prefetch, af-half-cache ----
// grid 768 = slice(6) x rowblock(128); block = 64 rows x 128 cols; wave = 32-col group.
// slice = b>>7: consecutive IDs share slice (r7-proven L2 ordering). 3 blocks/CU target
// from unified regs ~150 (af cache halved); NOT launch-bounds-forced (min stays 2).
__global__ __launch_bounds__(256, 2) void gemm_kernel(const float* __restrict__ x)
{
    __shared__ __align__(16) u16 xs[BM * XS_STRIDE];    // row-major x (af reads)
    __shared__ __align__(16) u16 xt[128 * XT_STRIDE];   // transposed x (xj reads)

    const int b     = blockIdx.x;
    const int slice = b >> 7;         // 0..5
    const int rb    = b & 127;        // 0..127
    const int row0  = rb * BM;
    const int tid   = threadIdx.x;
    const int lane  = tid & 63;
    const int wave  = tid >> 6;       // 0..3 -> col group [wave*32, +32)
    const int l15   = lane & 15;
    const int q     = lane >> 4;

    // stage x[row0..+64)[0..128) fp32 -> bf16 into xs (row-major) AND xt (transposed)
#pragma unroll
    for (int it = 0; it < 4; ++it) {
        const int c  = it*256 + tid;      // 1024 chunks of 8
        const int r  = c >> 4;            // 0..63
        const int c8 = (c & 15) * 8;
        const float* sp = x + ((size_t)(row0 + r) << 7) + c8;
        const floatx4 f0 = *(const floatx4*)(sp);
        const floatx4 f1 = *(const floatx4*)(sp + 4);
        ushort8 w;
#pragma unroll
        for (int e = 0; e < 4; ++e) { w[e] = f2bf_rne(f0[e]); w[4+e] = f2bf_rne(f1[e]); }
        *(ushort8*)&xs[r*XS_STRIDE + c8] = w;
#pragma unroll
        for (int e = 0; e < 8; ++e) xt[(c8 + e)*XT_STRIDE + r] = w[e];   // one-time cost
    }
    __syncthreads();

    // af cached for ks=0,1 only (32 VGPR); ks=2,3 re-read from LDS per phase.
    short8 af01[2][4];
#pragma unroll
    for (int ks = 0; ks < 2; ++ks)
#pragma unroll
        for (int mt = 0; mt < 4; ++mt)
            af01[ks][mt] = *(const short8*)&xs[(mt*16 + l15)*XS_STRIDE + ks*32 + q*8];

    const floatx4 fzero = {0.f, 0.f, 0.f, 0.f};
    floatx4 acc[4][2];
#pragma unroll
    for (int i = 0; i < 4; ++i) { acc[i][0] = fzero; acc[i][1] = fzero; }

    // phase partition: 129 phases over 6 slices (22,22,22,21,21,21)
    const int p0 = slice*21 + (slice < 3 ? slice : 3);
    const int np = 21 + (slice < 3 ? 1 : 0);

    const int colbase = wave*32;
    const size_t loff = (size_t)(colbase + l15)*32 + q*8;    // within-tile frag offset
    const int ktN = (p0 + np)*4;

    auto LOADB = [&](int ktl, short8* dst) {
        const u16* tb = g_B + (size_t)ktl*TILE_E + loff;
        dst[0] = *(const short8*)(tb);          // cols colbase..+15
        dst[1] = *(const short8*)(tb + 512);    // cols colbase+16..+31
    };

    // Two 4-kt buffer sets (r16-proven ~1-phase cover); af2/af3 + xj from LDS per phase.
    short8 Abuf[4][2], Bbuf[4][2];

#define DO_PHASE(CUR, NXT, PIDX, KTNXT)                                               \
    {                                                                                  \
        _Pragma("unroll")                                                              \
        for (int s = 0; s < 4; ++s) {                                                  \
            const int kl = (KTNXT) + s;                                                \
            LOADB(kl < ktN ? kl : ktN - 1, NXT[s]);                                    \
        }                                                                              \
        short8 af2[4], af3[4];                                                         \
        _Pragma("unroll")                                                              \
        for (int mt = 0; mt < 4; ++mt) {                                               \
            af2[mt] = *(const short8*)&xs[(mt*16 + l15)*XS_STRIDE + 64 + q*8];         \
            af3[mt] = *(const short8*)&xs[(mt*16 + l15)*XS_STRIDE + 96 + q*8];         \
        }                                                                              \
        const int pp_ = ((PIDX) < 128) ? (PIDX) : 0;                                   \
        ushortx4 xjr[4];                                                               \
        _Pragma("unroll")                                                              \
        for (int mt = 0; mt < 4; ++mt)                                                 \
            xjr[mt] = *(const ushortx4*)&xt[pp_*XT_STRIDE + mt*16 + q*4];              \
        floatx4 aj[4][2];                                                              \
        _Pragma("unroll")                                                              \
        for (int mt = 0; mt < 4; ++mt) {  /* ks=0: C-in = 0 */                         \
            aj[mt][0] = __builtin_amdgcn_mfma_f32_16x16x32_bf16(af01[0][mt], CUR[0][0], fzero, 0,0,0); \
            aj[mt][1] = __builtin_amdgcn_mfma_f32_16x16x32_bf16(af01[0][mt], CUR[0][1], fzero, 0,0,0); \
        }                                                                              \
        _Pragma("unroll")                                                              \
        for (int mt = 0; mt < 4; ++mt) {                                               \
            aj[mt][0] = __builtin_amdgcn_mfma_f32_16x16x32_bf16(af01[1][mt], CUR[1][0], aj[mt][0], 0,0,0); \
            aj[mt][1] = __builtin_amdgcn_mfma_f32_16x16x32_bf16(af01[1][mt], CUR[1][1], aj[mt][1], 0,0,0); \
        }                                                                              \
        _Pragma("unroll")                                                              \
        for (int mt = 0; mt < 4; ++mt) {                                               \
            aj[mt][0] = __builtin_amdgcn_mfma_f32_16x16x32_bf16(af2[mt], CUR[2][0], aj[mt][0], 0,0,0); \
            aj[mt][1] = __builtin_amdgcn_mfma_f32_16x16x32_bf16(af2[mt], CUR[2][1], aj[mt][1], 0,0,0); \
        }                                                                              \
        _Pragma("unroll")                                                              \
        for (int mt = 0; mt < 4; ++mt) {                                               \
            aj[mt][0] = __builtin_amdgcn_mfma_f32_16x16x32_bf16(af3[mt], CUR[3][0], aj[mt][0], 0,0,0); \
            aj[mt][1] = __builtin_amdgcn_mfma_f32_16x16x32_bf16(af3[mt], CUR[3][1], aj[mt][1], 0,0,0); \
        }                                                                              \
        _Pragma("unroll")                                                              \
        for (int mt = 0; mt < 4; ++mt) {                                               \
            floatx4 xjv;                                                               \
            _Pragma("unroll")                                                          \
            for (int r = 0; r < 4; ++r)                                                \
                xjv[r] = ((PIDX) < 128)                                                \
                    ? __uint_as_float(((unsigned int)xjr[mt][r]) << 16)                \
                    : 1.0f;                                                            \
            acc[mt][0] += xjv * aj[mt][0];                                             \
            acc[mt][1] += xjv * aj[mt][1];                                             \
        }                                                                              \
    }

    int kt = p0*4;
#pragma unroll
    for (int s = 0; s < 4; ++s) LOADB(kt + s, Abuf[s]);   // phase p0 (always valid)

    const int pairs = np >> 1;
    for (int j = 0; j < pairs; ++j) {
        const int p = p0 + 2*j;
        DO_PHASE(Abuf, Bbuf, p,     kt + 4);
        DO_PHASE(Bbuf, Abuf, p + 1, kt + 8);
        kt += 8;
    }
    if (np & 1) {                       // final odd phase (slices 3..5): consumes Abuf
        const int p = p0 + np - 1;
        DO_PHASE(Abuf, Bbuf, p, kt + 4);
    }
#undef DO_PHASE

    // slice-private plain stores (no atomics; region fully overwritten -> no zeroing)
    float* op = g_P + (size_t)slice * ((size_t)NROWS * 128);
#pragma unroll
    for (int mt = 0; mt < 4; ++mt)
#pragma unroll
        for (int nt = 0; nt < 2; ++nt) {
            const int col = colbase + nt*16 + l15;        // C/D: col = lane&15
#pragma unroll
            for (int r = 0; r < 4; ++r) {
                const int row = row0 + mt*16 + q*4 + r;   // C/D: row = q*4 + reg
                op[((size_t)row << 7) + col] = acc[mt][nt][r];
            }
        }
}

// ---------------- finish: reduce 6 slice partials, + bb, write fp32 ----------------
__global__ __launch_bounds__(256) void finish_kernel(
    const float* __restrict__ bb, float* __restrict__ out)
{
    const int flat = (blockIdx.x*256 + threadIdx.x) * 8;
    floatx4 s0 = {0.f, 0.f, 0.f, 0.f};
    floatx4 s1 = {0.f, 0.f, 0.f, 0.f};
#pragma unroll
    for (int s = 0; s < NSLICE; ++s) {
        const float* p = g_P + (size_t)s * ((size_t)NROWS * 128) + flat;
        const floatx4 a = *(const floatx4*)p;
        const floatx4 c = *(const floatx4*)(p + 4);
#pragma unroll
        for (int e = 0; e < 4; ++e) { s0[e] += a[e]; s1[e] += c[e]; }
    }
    const floatx4 b0 = *(const floatx4*)(bb + (flat & 127));
    const floatx4 b1 = *(const floatx4*)(bb + (flat & 127) + 4);
    floatx4 o0, o1;
#pragma unroll
    for (int e = 0; e < 4; ++e) { o0[e] = s0[e] + b0[e]; o1[e] = s1[e] + b1[e]; }
    *(floatx4*)(out + flat)     = o0;
    *(floatx4*)(out + flat + 4) = o1;
}

extern "C" void kernel_launch(void* const* d_in, const int* in_sizes, int n_in,
                              void* d_out, int out_size, void* d_ws, size_t ws_size,
                              hipStream_t stream) {
    (void)in_sizes; (void)n_in; (void)out_size; (void)d_ws; (void)ws_size;
    const float* x  = (const float*)d_in[0];
    const float* Wb = (const float*)d_in[1];
    const float* bb = (const float*)d_in[2];
    const float* Ww = (const float*)d_in[3];
    const float* bw = (const float*)d_in[4];
    float* out = (float*)d_out;

    prep_kernel  <<<dim3(NKT),            dim3(256), 0, stream>>>(Ww, Wb, bw);
    gemm_kernel  <<<dim3(768),            dim3(256), 0, stream>>>(x);
    finish_kernel<<<dim3(NROWS*128/2048), dim3(256), 0, stream>>>(bb, out);
}

// Round 16
// 117.134 us; speedup vs baseline: 1.1674x; 1.0619x over previous
//
#include <hip/hip_runtime.h>
#include <stdint.h>
#include <stddef.h>

// y[n,o] = sum_i x[n,i]*W[n,i,o] + b[n,o];  W = (x@Ww+bw) reshaped; b = x@Wb+bb.
// => Y = A@B (+bb): A[n, j*128+i] = x[n,i]*x[n,j]; B = Ww viewed [16384,128] row-major,
//    K-tail of 128: A[n,16384+i]=x[n,i], B[16384+i,o]=Wb[i,o]+bw[i*128+o].
// Per-j-phase factoring: aj = X_rows·B_j with raw-x fragments, acc += x[row,j]*aj.
// ROUND 23: r22 post-mortem — af-half-cache freed regs (VGPR 88) but occupancy FELL
// (14.5%) and bank conflicts hit 3.2M (xt scalar transposed writes): 57.5us. Sixth
// consecutive regression vs r16 (r17 57.2, r18 69.9, r19 51.0, r20 66.4, r22 57.5)
// across every mechanism class (TLP/regs/pipelining/setprio/LDS-staging/tile shape).
// r16 is the measured local optimum: residual ~50% dual-pipe-idle is dependent-load->
// MFMA latency at structurally low wave count; every overlap attempt cost more than it
// recovered. This round RESTORES r16 EXACTLY (current deployed kernel is r22, 8us
// worse). Expected: gemm 48.2-48.7us, VGPR 116, FETCH ~19.6MB, total ~116us. Final.

#define NROWS   8192
#define NKT     516            // (16384+128)/32 K-tiles
#define TILE_E  4096           // 128 cols x 32 kk per K-tile image (u16)
#define XS_STRIDE 136          // 128 + 8 pad for LDS x tile
#define LS_STRIDE 136
#define BM      128
#define NSLICE  8

typedef unsigned short u16;
typedef short short8 __attribute__((ext_vector_type(8)));
typedef unsigned short ushort8 __attribute__((ext_vector_type(8)));
typedef float floatx4 __attribute__((ext_vector_type(4)));

// Module-scope scratch (BSS; independent of d_ws — rounds 1-3 showed ws hazards).
__device__ __align__(16) u16   g_B[(size_t)NKT * TILE_E];                    // 4.2 MB bf16 B image
__device__ __align__(16) float g_P[(size_t)NSLICE * NROWS * 128];            // 33.5 MB fp32 partials

__device__ __forceinline__ u16 f2bf_rne(float f) {
    unsigned int u = __float_as_uint(f);
    u += 0x7fffu + ((u >> 16) & 1u);
    return (u16)(u >> 16);
}

// ---------------- prep: g_B[kt][o][kk] = B[kt*32+kk][o], coalesced via LDS transpose.
__global__ __launch_bounds__(256) void prep_kernel(
    const float* __restrict__ Ww, const float* __restrict__ Wb,
    const float* __restrict__ bw)
{
    __shared__ __align__(16) u16 ls[32 * LS_STRIDE];
    const int kt = blockIdx.x;
    const int t  = threadIdx.x;

    // load 16 contiguous floats -> bf16, store to ls[kk][o] (padded stride)
    float v[16];
    if (kt < 512) {
        const float* src = Ww + (size_t)(kt >> 2)*16384 + (size_t)(kt & 3)*32*128 + t*16;
#pragma unroll
        for (int c = 0; c < 4; ++c) {
            const floatx4 f4 = *(const floatx4*)(src + c*4);
#pragma unroll
            for (int e = 0; e < 4; ++e) v[c*4 + e] = f4[e];
        }
    } else {
        const size_t base = (size_t)(kt - 512)*32*128 + t*16;
        const float* s1 = Wb + base;
        const float* s2 = bw + base;
#pragma unroll
        for (int c = 0; c < 4; ++c) {
            const floatx4 a = *(const floatx4*)(s1 + c*4);
            const floatx4 b = *(const floatx4*)(s2 + c*4);
#pragma unroll
            for (int e = 0; e < 4; ++e) v[c*4 + e] = a[e] + b[e];
        }
    }
    {
        const int kk = t >> 3;            // f = t*16 -> kk = f>>7
        const int o0 = (t & 7) * 16;      // f & 127
        ushort8 w0, w1;
#pragma unroll
        for (int e = 0; e < 8; ++e) { w0[e] = f2bf_rne(v[e]); w1[e] = f2bf_rne(v[8+e]); }
        *(ushort8*)&ls[kk*LS_STRIDE + o0]     = w0;
        *(ushort8*)&ls[kk*LS_STRIDE + o0 + 8] = w1;
    }
    __syncthreads();
    // write out [o][kk]: thread t covers d = t*16..+15 -> o = t>>1, kk = (t&1)*16..+15
    {
        const int o   = t >> 1;
        const int kk0 = (t & 1) * 16;
        ushort8 w0, w1;
#pragma unroll
        for (int e = 0; e < 8; ++e) {
            w0[e] = ls[(kk0 + e)*LS_STRIDE + o];
            w1[e] = ls[(kk0 + 8 + e)*LS_STRIDE + o];
        }
        u16* outp = g_B + (size_t)kt*TILE_E + t*16;
        ((ushort8*)outp)[0] = w0; ((ushort8*)outp)[1] = w1;
    }
}

// ---------------- gemm: 8-wave block, 128x128 tile, dbuf B prefetch ----------------
// grid 512 = slice(8) x rowblock(64); block tile 128 rows x 128 cols; 2 blocks/CU
// (16 waves/CU). slice = b>>6: consecutive IDs share slice (r7-proven L2 ordering).
// Per wave: 64x32 sub-tile, r13-proven DO_PHASE pipeline with packed xjv tail.
__global__ __launch_bounds__(512, 2) void gemm_kernel(const float* __restrict__ x)
{
    __shared__ __align__(16) u16 xs[BM * XS_STRIDE];

    const int b     = blockIdx.x;
    const int slice = b >> 6;         // 0..7
    const int rb    = b & 63;         // 0..63
    const int row0  = rb * BM;
    const int tid   = threadIdx.x;
    const int lane  = tid & 63;
    const int wave  = tid >> 6;       // 0..7
    const int wm    = wave >> 2;      // row group: rows [wm*64, +64)
    const int wc    = wave & 3;       // col subgroup: cols [wc*32, +32)
    const int l15   = lane & 15;
    const int q     = lane >> 4;

    // stage x[row0..+128)[0..128) fp32 -> bf16 xs (512 threads: 4 iters)
#pragma unroll
    for (int it = 0; it < 4; ++it) {
        const int c  = it*512 + tid;
        const int r  = c >> 4;
        const int c8 = (c & 15) * 8;
        const float* sp = x + ((size_t)(row0 + r) << 7) + c8;
        const floatx4 f0 = *(const floatx4*)(sp);
        const floatx4 f1 = *(const floatx4*)(sp + 4);
        ushort8 w;
#pragma unroll
        for (int e = 0; e < 4; ++e) { w[e] = f2bf_rne(f0[e]); w[4+e] = f2bf_rne(f1[e]); }
        *(ushort8*)&xs[r*XS_STRIDE + c8] = w;
    }
    __syncthreads();

    // A-fragments cached (phase-invariant): af[ks][mt], A[m=l15][k=q*8+e]
    short8 af[4][4];
#pragma unroll
    for (int ks = 0; ks < 4; ++ks)
#pragma unroll
        for (int mt = 0; mt < 4; ++mt)
            af[ks][mt] = *(const short8*)&xs[(wm*64 + mt*16 + l15)*XS_STRIDE + ks*32 + q*8];

    const floatx4 fzero = {0.f, 0.f, 0.f, 0.f};
    floatx4 acc[4][2];
#pragma unroll
    for (int i = 0; i < 4; ++i) { acc[i][0] = fzero; acc[i][1] = fzero; }

    // phase partition: 129 phases over 8 slices (17,16,16,16,16,16,16,16)
    const int p0 = slice*16 + (slice ? 1 : 0);
    const int np = slice ? 16 : 17;

    const int colbase = wc*32;
    const size_t loff = (size_t)(colbase + l15)*32 + q*8;    // within-tile frag offset
    const int ktN = (p0 + np)*4;

    auto LOADB = [&](int ktl, short8* dst) {
        const u16* tb = g_B + (size_t)ktl*TILE_E + loff;
        dst[0] = *(const short8*)(tb);          // cols colbase..+15
        dst[1] = *(const short8*)(tb + 512);    // cols colbase+16..+31
    };

    // Two 4-kt buffer sets; phase p computes from CUR while all 8 loads for phase p+1
    // go to NXT. All indices compile-time after unroll (rule: no runtime-indexed regs).
    short8 Abuf[4][2], Bbuf[4][2];

#define DO_PHASE(CUR, NXT, PIDX, KTNXT)                                               \
    {                                                                                  \
        _Pragma("unroll")                                                              \
        for (int s = 0; s < 4; ++s) {                                                  \
            const int kl = (KTNXT) + s;                                                \
            LOADB(kl < ktN ? kl : ktN - 1, NXT[s]);                                    \
        }                                                                              \
        floatx4 aj[4][2];                                                              \
        _Pragma("unroll")                                                              \
        for (int mt = 0; mt < 4; ++mt) {  /* ks=0: C-in = 0 */                         \
            aj[mt][0] = __builtin_amdgcn_mfma_f32_16x16x32_bf16(af[0][mt], CUR[0][0], fzero, 0,0,0); \
            aj[mt][1] = __builtin_amdgcn_mfma_f32_16x16x32_bf16(af[0][mt], CUR[0][1], fzero, 0,0,0); \
        }                                                                              \
        _Pragma("unroll")                                                              \
        for (int mt = 0; mt < 4; ++mt) {                                               \
            aj[mt][0] = __builtin_amdgcn_mfma_f32_16x16x32_bf16(af[1][mt], CUR[1][0], aj[mt][0], 0,0,0); \
            aj[mt][1] = __builtin_amdgcn_mfma_f32_16x16x32_bf16(af[1][mt], CUR[1][1], aj[mt][1], 0,0,0); \
        }                                                                              \
        _Pragma("unroll")                                                              \
        for (int mt = 0; mt < 4; ++mt) {                                               \
            aj[mt][0] = __builtin_amdgcn_mfma_f32_16x16x32_bf16(af[2][mt], CUR[2][0], aj[mt][0], 0,0,0); \
            aj[mt][1] = __builtin_amdgcn_mfma_f32_16x16x32_bf16(af[2][mt], CUR[2][1], aj[mt][1], 0,0,0); \
        }                                                                              \
        _Pragma("unroll")                                                              \
        for (int mt = 0; mt < 4; ++mt) {                                               \
            aj[mt][0] = __builtin_amdgcn_mfma_f32_16x16x32_bf16(af[3][mt], CUR[3][0], aj[mt][0], 0,0,0); \
            aj[mt][1] = __builtin_amdgcn_mfma_f32_16x16x32_bf16(af[3][mt], CUR[3][1], aj[mt][1], 0,0,0); \
        }                                                                              \
        _Pragma("unroll")                                                              \
        for (int mt = 0; mt < 4; ++mt) {                                               \
            floatx4 xjv;                                                               \
            _Pragma("unroll")                                                          \
            for (int r = 0; r < 4; ++r) {                                              \
                const int rl = wm*64 + mt*16 + q*4 + r;   /* C/D: row = q*4 + reg */   \
                xjv[r] = ((PIDX) < 128)                                                \
                    ? __uint_as_float(((unsigned int)xs[rl*XS_STRIDE + (PIDX)]) << 16) \
                    : 1.0f;                                                            \
            }                                                                          \
            acc[mt][0] += xjv * aj[mt][0];                                             \
            acc[mt][1] += xjv * aj[mt][1];                                             \
        }                                                                              \
    }

    int kt = p0*4;
#pragma unroll
    for (int s = 0; s < 4; ++s) LOADB(kt + s, Abuf[s]);   // phase p0 (always valid)

    const int pairs = np >> 1;
    for (int j = 0; j < pairs; ++j) {
        const int p = p0 + 2*j;
        DO_PHASE(Abuf, Bbuf, p,     kt + 4);
        DO_PHASE(Bbuf, Abuf, p + 1, kt + 8);
        kt += 8;
    }
    if (np & 1) {                       // final odd phase (slice 0): consumes Abuf
        const int p = p0 + np - 1;
        DO_PHASE(Abuf, Bbuf, p, kt + 4);
    }
#undef DO_PHASE

    // slice-private plain stores (no atomics; region fully overwritten -> no zeroing)
    float* op = g_P + (size_t)slice * ((size_t)NROWS * 128);
#pragma unroll
    for (int mt = 0; mt < 4; ++mt)
#pragma unroll
        for (int nt = 0; nt < 2; ++nt) {
            const int col = colbase + nt*16 + l15;        // C/D: col = lane&15
#pragma unroll
            for (int r = 0; r < 4; ++r) {
                const int row = row0 + wm*64 + mt*16 + q*4 + r;
                op[((size_t)row << 7) + col] = acc[mt][nt][r];
            }
        }
}

// ---------------- finish: reduce 8 slice partials, + bb, write fp32 ----------------
__global__ __launch_bounds__(256) void finish_kernel(
    const float* __restrict__ bb, float* __restrict__ out)
{
    const int flat = (blockIdx.x*256 + threadIdx.x) * 8;
    floatx4 s0 = {0.f, 0.f, 0.f, 0.f};
    floatx4 s1 = {0.f, 0.f, 0.f, 0.f};
#pragma unroll
    for (int s = 0; s < NSLICE; ++s) {
        const float* p = g_P + (size_t)s * ((size_t)NROWS * 128) + flat;
        const floatx4 a = *(const floatx4*)p;
        const floatx4 c = *(const floatx4*)(p + 4);
#pragma unroll
        for (int e = 0; e < 4; ++e) { s0[e] += a[e]; s1[e] += c[e]; }
    }
    const floatx4 b0 = *(const floatx4*)(bb + (flat & 127));
    const floatx4 b1 = *(const floatx4*)(bb + (flat & 127) + 4);
    floatx4 o0, o1;
#pragma unroll
    for (int e = 0; e < 4; ++e) { o0[e] = s0[e] + b0[e]; o1[e] = s1[e] + b1[e]; }
    *(floatx4*)(out + flat)     = o0;
    *(floatx4*)(out + flat + 4) = o1;
}

extern "C" void kernel_launch(void* const* d_in, const int* in_sizes, int n_in,
                              void* d_out, int out_size, void* d_ws, size_t ws_size,
                              hipStream_t stream) {
    (void)in_sizes; (void)n_in; (void)out_size; (void)d_ws; (void)ws_size;
    const float* x  = (const float*)d_in[0];
    const float* Wb = (const float*)d_in[1];
    const float* bb = (const float*)d_in[2];
    const float* Ww = (const float*)d_in[3];
    const float* bw = (const float*)d_in[4];
    float* out = (float*)d_out;

    prep_kernel  <<<dim3(NKT),            dim3(256), 0, stream>>>(Ww, Wb, bw);
    gemm_kernel  <<<dim3(512),            dim3(512), 0, stream>>>(x);
    finish_kernel<<<dim3(NROWS*128/2048), dim3(256), 0, stream>>>(bb, out);
}